// Round 16
// baseline (84.254 us; speedup 1.0000x reference)
//
#include <hip/hip_runtime.h>
#include <stdint.h>

#define NXS    65536
#define HID    32
#define BTL    512           // 8 waves per block
#define NB     256           // 1 block/CU
#define OWNB   256           // cells owned per block
#define MARG   200           // halo per side (single launch, T=200)
#define SSPAN  656           // cells spanned per block
#define SLAB   128           // cells per wave slab (2 per lane)
#define EPOCH  24            // steps between refills (even!)
#define SAFE_T 48            // exact-mode steps before lag mode
#define LUT_N  1024          // bins over [-0.25, 1.75]
#define NREP   16
#define LUT_SC 512.0f        // bins per unit c
#define LUT_BF 128.0f        // -lo*scale

typedef float    f32x4 __attribute__((ext_vector_type(4)));
typedef uint32_t u32x4 __attribute__((ext_vector_type(4)));

__device__ __forceinline__ float fexp2(float x) { return __builtin_amdgcn_exp2f(x); }
__device__ __forceinline__ float frcp(float x)  { return __builtin_amdgcn_rcpf(x); }
__device__ __forceinline__ float flog2(float x) { return __builtin_amdgcn_logf(x); }

__device__ __forceinline__ float dpp_up(float x) {
    int xi = __float_as_int(x);
    return __int_as_float(__builtin_amdgcn_update_dpp(xi, xi, 0x138, 0xF, 0xF, false));
}
__device__ __forceinline__ float dpp_down(float x) {
    int xi = __float_as_int(x);
    return __int_as_float(__builtin_amdgcn_update_dpp(xi, xi, 0x130, 0xF, 0xF, false));
}

__device__ __forceinline__ float fast_tanh(float x) {
    x = fminf(fmaxf(x, -15.0f), 15.0f);
    float e = fexp2(x * 2.8853900817779268f);
    return (e - 1.0f) * frcp(e + 1.0f);
}
__device__ __forceinline__ float fast_sigmoid(float x) {
    float e = fexp2(x * -1.4426950408889634f);
    return frcp(1.0f + e);
}

struct FinnW {
    const float* W0; const float* b0; const float* W1; const float* b1;
    const float* W2; const float* b2; const float* W3; const float* b3;
    const float* ret_fac;
};
struct FinnPtrs {
    const float* tvec;
    const float* Dp;  const float* stencil; const float* BCp; const float* fp;
    const float* kdp; const float* betap;   const float* alphap; const float* rhosp;
    const float* nep; const float* vep;     const float* dxp;
};

__device__ float mlp_ret(float c, const FinnW& W) {
    float h[HID], a[HID];
    #pragma unroll
    for (int j = 0; j < HID; ++j)
        h[j] = fast_tanh(fmaf(c, W.W0[j], W.b0[j]));
    #pragma unroll
    for (int j = 0; j < HID; ++j) a[j] = W.b1[j];
    #pragma unroll
    for (int k = 0; k < HID; ++k) {
        const float hk = h[k];
        #pragma unroll
        for (int j = 0; j < HID; ++j) a[j] = fmaf(hk, W.W1[k * HID + j], a[j]);
    }
    #pragma unroll
    for (int j = 0; j < HID; ++j) h[j] = fast_tanh(a[j]);
    #pragma unroll
    for (int j = 0; j < HID; ++j) a[j] = W.b2[j];
    #pragma unroll
    for (int k = 0; k < HID; ++k) {
        const float hk = h[k];
        #pragma unroll
        for (int j = 0; j < HID; ++j) a[j] = fmaf(hk, W.W2[k * HID + j], a[j]);
    }
    #pragma unroll
    for (int j = 0; j < HID; ++j) h[j] = fast_tanh(a[j]);
    float pre = W.b3[0];
    #pragma unroll
    for (int k = 0; k < HID; ++k) pre = fmaf(h[k], W.W3[k], pre);
    return fast_sigmoid(pre) * W.ret_fac[0];
}

// ---- single fused kernel: build LUT in LDS, then epoch-refill sweep ----
__global__ __launch_bounds__(BTL, 2) void finn_all(
    const float* __restrict__ uin, float* __restrict__ out,
    FinnW W, FinnPtrs P, int T, uint32_t outBytes)
{
    __shared__ float2 slut[LUT_N * NREP];   // (slope, icpt) ×16 copies, 128 KB
    __shared__ float2 xbuf[SSPAN];          // refill exchange; scratch during build

    const int tid  = threadIdx.x;
    const int w    = tid >> 6;
    const int lane = tid & 63;
    const int r15  = lane & 15;

    // ---- build LUT in-LDS: nodes c_i = -0.25 + i/512, i = tid, tid+512 ----
    float* raw = (float*)xbuf;              // 1024 floats scratch
    raw[tid]       = mlp_ret(-0.25f + (float)tid * (1.0f / LUT_SC), W);
    raw[tid + 512] = mlp_ret(-0.25f + (float)(tid + 512) * (1.0f / LUT_SC), W);
    __syncthreads();
    #pragma unroll
    for (int q = 0; q < 2; ++q) {
        const int bin = tid + q * 512;
        const float r0 = raw[bin];
        const float r1 = (bin == LUT_N - 1) ? r0 : raw[bin + 1];
        const float sl = (r1 - r0) * LUT_SC;
        const float ic = fmaf(-(float)(bin - 128), r1 - r0, r0); // r0 - sl*node
        const float2 e = make_float2(sl, ic);
        #pragma unroll
        for (int r = 0; r < NREP; ++r) slut[(bin << 4) | r] = e;
    }

    // wave-uniform scalars
    const float dt   = P.tvec[1] - P.tvec[0];
    const float s0   = P.stencil[0];
    const float s1   = P.stencil[1];
    const float dx   = P.dxp[0];
    const float A    = P.Dp[0] / (dx * dx);
    const float B    = P.vep[0] / dx;
    const float BC   = P.BCp[0];
    const float beta = P.betap[0];
    const float alp  = P.alphap[0];
    const float akd  = (1.0f - P.fp[0]) * P.kdp[0];
    const float rsne = P.rhosp[0] / P.nep[0];

    const float G     = dt * rsne * alp;
    const float mGAKD = -G * akd;
    const float S1c   = 1.0f - dt * alp;
    const float S2c   = dt * alp * akd;
    const float K1u   = dt * (2.0f * A * s0 - B);
    const float K2u   = dt * (A * s1 + B);
    const float K3u   = dt * A * s1;

    const int b = blockIdx.x;
    int blockBase = b * OWNB - MARG;
    if (blockBase < 0) blockBase = 0;
    if (blockBase > NXS - SSPAN) blockBase = NXS - SSPAN;
    const bool leftA  = (blockBase == 0);
    const bool rightA = (blockBase == NXS - SSPAN);
    const int ownRelL = b * OWNB - blockBase;
    const int ownRelR = ownRelL + OWNB;

    u32x4 srd;
    {
        const uint64_t op = (uint64_t)(uintptr_t)out;
        srd.x = (uint32_t)op;
        srd.y = (uint32_t)(op >> 32);
        srd.z = outBytes;
        srd.w = 0x00020000u;
    }

    int a = ((SSPAN - SLAB) * w / 7 + 1) & ~1;

    float c0, sk0, c1, sk1;
    {
        const f32x4* u4 = (const f32x4*)uin;
        const f32x4 u = u4[(blockBase + a + lane * 2) >> 1];
        c0 = u.x; sk0 = u.y; c1 = u.z; sk1 = u.w;
    }

    __syncthreads();   // LUT ready (also covers raw-scratch reuse)

    int done = 0;
    while (done < T) {
        int nst = T - done; if (nst > EPOCH) nst = EPOCH;
        const int si = a + lane * 2;
        const int g0 = blockBase + si;

        float K0_0 = 0.0f, K1_0 = K1u, K2_0 = K2u;
        const float K3_0 = K3u;
        float K1_1 = K1u, K3_1 = K3u;
        const float K2_1 = K2u;
        if (g0 == 0)           { K0_0 = dt * BC * (2.0f * A * s1 + B);
                                 K1_0 = dt * (3.0f * A * s0 - B); K2_0 = 0.0f; }
        if (g0 + 1 == NXS - 1) { K1_1 = dt * (2.0f * A * s0 - B + A * s1);
                                 K3_1 = 0.0f; }

        const int vL = leftA ? 0 : done;
        const int vR = rightA ? SSPAN : SSPAN - done;
        const int pd = vR - vL - SLAB;
        const int aPrev = vL + ((pd * (w - 1) / 7 + 1) & ~1);
        const int aNext = vL + ((pd * (w + 1) / 7 + 1) & ~1);
        int bLo = (w == 0) ? 0     : (((aPrev + SLAB + a) >> 1) & ~1);
        int bHi = (w == 7) ? SSPAN : (((a + SLAB + aNext) >> 1) & ~1);
        if (bLo < ownRelL) bLo = ownRelL;
        if (bHi > ownRelR) bHi = ownRelR;
        const bool st = (si >= bLo) && (si < bHi);
        uint32_t voff = st ? (uint32_t)((done * NXS + g0) * 8) : 0x60000000u;

        // epoch prologue: DPP + fetch (slope,icpt) @ current c  (exact for iter 0)
        float clS = dpp_up(c1);
        float crS = dpp_down(c0);
        int i0 = (int)__builtin_amdgcn_fmed3f(fmaf(c0, LUT_SC, LUT_BF), 0.0f, 1023.0f);
        int i1 = (int)__builtin_amdgcn_fmed3f(fmaf(c1, LUT_SC, LUT_BF), 0.0f, 1023.0f);
        float2 E0 = slut[(i0 << 4) | r15];
        float2 E1 = slut[(i1 << 4) | r15];

        if (done < SAFE_T) {
            // ---- EXACT mode: fetch after update (chain-exposed) ----
            for (int s = 0; s < nst; ++s) {
                float t0 = fmaf(K1_0, c0, K0_0);
                t0 = fmaf(K2_0, clS, t0);
                t0 = fmaf(K3_0, c1, t0);
                float t1 = K1_1 * c1;
                t1 = fmaf(K2_1, c0, t1);
                t1 = fmaf(K3_1, crS, t1);

                const float ret0 = fmaf(c0, E0.x, E0.y);
                const float ret1 = fmaf(c1, E1.x, E1.y);
                const float pw0 = fexp2(beta * flog2(fmaxf(c0, 1e-9f)));
                const float pw1 = fexp2(beta * flog2(fmaxf(c1, 1e-9f)));

                float v0 = fmaf(ret0, t0, c0); v0 = fmaf(mGAKD, pw0, v0);
                float v1 = fmaf(ret1, t1, c1); v1 = fmaf(mGAKD, pw1, v1);
                const float nc0 = fmaf(G, sk0, v0);
                const float nc1 = fmaf(G, sk1, v1);
                sk0 = fmaf(S1c, sk0, S2c * pw0);
                sk1 = fmaf(S1c, sk1, S2c * pw1);
                c0 = nc0; c1 = nc1;

                i0 = (int)__builtin_amdgcn_fmed3f(fmaf(c0, LUT_SC, LUT_BF), 0.0f, 1023.0f);
                i1 = (int)__builtin_amdgcn_fmed3f(fmaf(c1, LUT_SC, LUT_BF), 0.0f, 1023.0f);
                E0 = slut[(i0 << 4) | r15];
                E1 = slut[(i1 << 4) | r15];
                clS = dpp_up(c1);
                crS = dpp_down(c0);

                f32x4 ov; ov.x = c0; ov.y = sk0; ov.z = c1; ov.w = sk1;
                asm volatile("buffer_store_dwordx4 %0, %1, %2, 0 offen"
                             :: "v"(ov), "v"(voff), "s"(srd) : "memory");
                voff += (uint32_t)(NXS * 8);
            }
        } else {
            // ---- LAG mode: fetch at top indexed by CURRENT c, consume next iter ----
            for (int s = 0; s < nst; ++s) {
                // issue next-iter fetch now: a full body of slack hides LDS latency
                const int n0 = (int)__builtin_amdgcn_fmed3f(fmaf(c0, LUT_SC, LUT_BF), 0.0f, 1023.0f);
                const int n1 = (int)__builtin_amdgcn_fmed3f(fmaf(c1, LUT_SC, LUT_BF), 0.0f, 1023.0f);
                const float2 EN0 = slut[(n0 << 4) | r15];
                const float2 EN1 = slut[(n1 << 4) | r15];

                float t0 = fmaf(K1_0, c0, K0_0);
                t0 = fmaf(K2_0, clS, t0);
                t0 = fmaf(K3_0, c1, t0);
                float t1 = K1_1 * c1;
                t1 = fmaf(K2_1, c0, t1);
                t1 = fmaf(K3_1, crS, t1);

                // E0/E1 fetched last iter (lag-1 expansion point), evaluated at current c
                const float ret0 = fmaf(c0, E0.x, E0.y);
                const float ret1 = fmaf(c1, E1.x, E1.y);
                const float pw0 = fexp2(beta * flog2(fmaxf(c0, 1e-9f)));
                const float pw1 = fexp2(beta * flog2(fmaxf(c1, 1e-9f)));

                float v0 = fmaf(ret0, t0, c0); v0 = fmaf(mGAKD, pw0, v0);
                float v1 = fmaf(ret1, t1, c1); v1 = fmaf(mGAKD, pw1, v1);
                const float nc0 = fmaf(G, sk0, v0);
                const float nc1 = fmaf(G, sk1, v1);
                sk0 = fmaf(S1c, sk0, S2c * pw0);
                sk1 = fmaf(S1c, sk1, S2c * pw1);
                c0 = nc0; c1 = nc1;

                clS = dpp_up(c1);
                crS = dpp_down(c0);
                E0 = EN0; E1 = EN1;

                f32x4 ov; ov.x = c0; ov.y = sk0; ov.z = c1; ov.w = sk1;
                asm volatile("buffer_store_dwordx4 %0, %1, %2, 0 offen"
                             :: "v"(ov), "v"(voff), "s"(srd) : "memory");
                voff += (uint32_t)(NXS * 8);
            }
        }

        done += nst;
        if (done >= T) break;

        // ---- refill: LDS-only barriers (stores stay in flight) ----
        asm volatile("s_waitcnt lgkmcnt(0)" ::: "memory");
        __builtin_amdgcn_s_barrier();
        asm volatile("" ::: "memory");
        {
            const int wLo = (w == 0 && leftA)  ? 0    : EPOCH;
            const int wHi = (w == 7 && rightA) ? SLAB : SLAB - EPOCH;
            const int sr = lane * 2;
            if (sr >= wLo && sr < wHi)         xbuf[a + sr]     = make_float2(c0, sk0);
            if (sr + 1 >= wLo && sr + 1 < wHi) xbuf[a + sr + 1] = make_float2(c1, sk1);
        }
        asm volatile("s_waitcnt lgkmcnt(0)" ::: "memory");
        __builtin_amdgcn_s_barrier();
        asm volatile("" ::: "memory");
        {
            const int vL2 = leftA ? 0 : done;
            const int vR2 = rightA ? SSPAN : SSPAN - done;
            const int pd2 = vR2 - vL2 - SLAB;
            a = vL2 + ((pd2 * w / 7 + 1) & ~1);
            const f32x4 u = *(const f32x4*)&xbuf[a + lane * 2];
            c0 = u.x; sk0 = u.y; c1 = u.z; sk1 = u.w;
        }
        asm volatile("s_waitcnt lgkmcnt(0)" ::: "memory");
        __builtin_amdgcn_s_barrier();
        asm volatile("" ::: "memory");
    }
}

extern "C" void kernel_launch(void* const* d_in, const int* in_sizes, int n_in,
                              void* d_out, int out_size, void* d_ws, size_t ws_size,
                              hipStream_t stream)
{
    const float* u0 = (const float*)d_in[0];
    FinnW W;
    FinnPtrs P;
    P.tvec    = (const float*)d_in[1];
    W.W0      = (const float*)d_in[2];
    W.b0      = (const float*)d_in[3];
    W.W1      = (const float*)d_in[4];
    W.b1      = (const float*)d_in[5];
    W.W2      = (const float*)d_in[6];
    W.b2      = (const float*)d_in[7];
    W.W3      = (const float*)d_in[8];
    W.b3      = (const float*)d_in[9];
    W.ret_fac = (const float*)d_in[10];
    P.Dp      = (const float*)d_in[11];
    P.stencil = (const float*)d_in[12];
    P.BCp     = (const float*)d_in[13];
    P.fp      = (const float*)d_in[14];
    P.kdp     = (const float*)d_in[15];
    P.betap   = (const float*)d_in[16];
    P.alphap  = (const float*)d_in[17];
    P.rhosp   = (const float*)d_in[18];
    P.nep     = (const float*)d_in[19];
    P.vep     = (const float*)d_in[20];
    P.dxp     = (const float*)d_in[21];

    float* out  = (float*)d_out;
    const int T = in_sizes[1];          // 200

    hipLaunchKernelGGL(finn_all, dim3(NB), dim3(BTL), 0, stream,
                       u0, out, W, P, T, (uint32_t)out_size * 4u);
}

// Round 17
// 66.223 us; speedup vs baseline: 1.2723x; 1.2723x over previous
//
#include <hip/hip_runtime.h>
#include <stdint.h>

#define NXS    65536
#define HID    32
#define BTL    512           // 8 waves per block
#define NB     256           // 1 block/CU
#define OWNB   256           // cells owned per block
#define MARG   200           // halo per side (single launch, T=200)
#define SSPAN  656           // cells spanned per block
#define SLAB   128           // cells per wave slab (2 per lane)
#define EPOCH  24            // steps between refills (even!)
#define SAFE_T 48            // exact-mode steps (rough field) before lag mode
#define LUT_N  512           // bins over [-0.25, 1.75]
#define NREP   16
#define LUT_SC 256.0f        // bins per unit c
#define LUT_BF 64.0f         // -lo*scale = 0.25*256

typedef float    f32x4 __attribute__((ext_vector_type(4)));
typedef uint32_t u32x4 __attribute__((ext_vector_type(4)));

__device__ __forceinline__ float fexp2(float x) { return __builtin_amdgcn_exp2f(x); }
__device__ __forceinline__ float frcp(float x)  { return __builtin_amdgcn_rcpf(x); }
__device__ __forceinline__ float flog2(float x) { return __builtin_amdgcn_logf(x); }

__device__ __forceinline__ float dpp_up(float x) {
    int xi = __float_as_int(x);
    return __int_as_float(__builtin_amdgcn_update_dpp(xi, xi, 0x138, 0xF, 0xF, false));
}
__device__ __forceinline__ float dpp_down(float x) {
    int xi = __float_as_int(x);
    return __int_as_float(__builtin_amdgcn_update_dpp(xi, xi, 0x130, 0xF, 0xF, false));
}

__device__ __forceinline__ float fast_tanh(float x) {
    x = fminf(fmaxf(x, -15.0f), 15.0f);
    float e = fexp2(x * 2.8853900817779268f);
    return (e - 1.0f) * frcp(e + 1.0f);
}
__device__ __forceinline__ float fast_sigmoid(float x) {
    float e = fexp2(x * -1.4426950408889634f);
    return frcp(1.0f + e);
}

struct FinnPtrs {
    const float* tvec;
    const float* Dp;  const float* stencil; const float* BCp; const float* fp;
    const float* kdp; const float* betap;   const float* alphap; const float* rhosp;
    const float* nep; const float* vep;     const float* dxp;
};

// ---- Kernel 1: raw (ret, pw) at LUT_N+1 nodes, c_i = -0.25 + i/256 ----
__global__ __launch_bounds__(256) void finn_lut(
    const float* __restrict__ W0, const float* __restrict__ b0,
    const float* __restrict__ W1, const float* __restrict__ b1,
    const float* __restrict__ W2, const float* __restrict__ b2,
    const float* __restrict__ W3, const float* __restrict__ b3,
    const float* __restrict__ ret_fac, const float* __restrict__ betap,
    float2* __restrict__ raw)
{
    const int i = blockIdx.x * 256 + threadIdx.x;
    if (i > LUT_N) return;
    const float c = -0.25f + (float)i * (1.0f / LUT_SC);

    float h[HID], a[HID];
    #pragma unroll
    for (int j = 0; j < HID; ++j)
        h[j] = fast_tanh(fmaf(c, W0[j], b0[j]));

    #pragma unroll
    for (int j = 0; j < HID; ++j) a[j] = b1[j];
    #pragma unroll
    for (int k = 0; k < HID; ++k) {
        const float hk = h[k];
        #pragma unroll
        for (int j = 0; j < HID; ++j) a[j] = fmaf(hk, W1[k * HID + j], a[j]);
    }
    #pragma unroll
    for (int j = 0; j < HID; ++j) h[j] = fast_tanh(a[j]);

    #pragma unroll
    for (int j = 0; j < HID; ++j) a[j] = b2[j];
    #pragma unroll
    for (int k = 0; k < HID; ++k) {
        const float hk = h[k];
        #pragma unroll
        for (int j = 0; j < HID; ++j) a[j] = fmaf(hk, W2[k * HID + j], a[j]);
    }
    #pragma unroll
    for (int j = 0; j < HID; ++j) h[j] = fast_tanh(a[j]);

    float pre = b3[0];
    #pragma unroll
    for (int k = 0; k < HID; ++k) pre = fmaf(h[k], W3[k], pre);

    const float ret = fast_sigmoid(pre) * ret_fac[0];
    const float pw  = fexp2(betap[0] * flog2(fmaxf(c, 1e-9f)));
    raw[i] = make_float2(ret, pw);
}

// ---- Kernel 2: R15 structure; linearized LUT; exact mode then lag mode ----
__global__ __launch_bounds__(BTL, 2) void finn_sweep(
    const float* __restrict__ uin, float* __restrict__ out,
    const float2* __restrict__ raw, FinnPtrs P, int T, uint32_t outBytes)
{
    __shared__ f32x4  slut[LUT_N * NREP];   // (ret_sl,ret_ic,pw_sl,pw_ic) ×16, 128 KB
    __shared__ float2 xbuf[SSPAN];          // refill exchange

    const int tid  = threadIdx.x;
    const int w    = tid >> 6;
    const int lane = tid & 63;
    const int r15  = lane & 15;

    // stage: build slopes from raw nodes (global, L2-shared), replicate ×16
    if (tid < LUT_N) {
        const float2 r0 = raw[tid];
        const float2 r1 = raw[tid + 1];
        const float nodec = -0.25f + (float)tid * (1.0f / LUT_SC);
        f32x4 e;
        e.x = (r1.x - r0.x) * LUT_SC;  e.y = fmaf(-nodec, e.x, r0.x);
        e.z = (r1.y - r0.y) * LUT_SC;  e.w = fmaf(-nodec, e.z, r0.y);
        #pragma unroll
        for (int r = 0; r < NREP; ++r) slut[(tid << 4) | r] = e;
    }

    // wave-uniform scalars
    const float dt   = P.tvec[1] - P.tvec[0];
    const float s0   = P.stencil[0];
    const float s1   = P.stencil[1];
    const float dx   = P.dxp[0];
    const float A    = P.Dp[0] / (dx * dx);
    const float B    = P.vep[0] / dx;
    const float BC   = P.BCp[0];
    const float alp  = P.alphap[0];
    const float akd  = (1.0f - P.fp[0]) * P.kdp[0];
    const float rsne = P.rhosp[0] / P.nep[0];

    const float G     = dt * rsne * alp;
    const float mGAKD = -G * akd;
    const float S1c   = 1.0f - dt * alp;
    const float S2c   = dt * alp * akd;
    const float K1u   = dt * (2.0f * A * s0 - B);
    const float K2u   = dt * (A * s1 + B);
    const float K3u   = dt * A * s1;

    const int b = blockIdx.x;
    int blockBase = b * OWNB - MARG;
    if (blockBase < 0) blockBase = 0;
    if (blockBase > NXS - SSPAN) blockBase = NXS - SSPAN;
    const bool leftA  = (blockBase == 0);
    const bool rightA = (blockBase == NXS - SSPAN);
    const int ownRelL = b * OWNB - blockBase;
    const int ownRelR = ownRelL + OWNB;

    u32x4 srd;
    {
        const uint64_t op = (uint64_t)(uintptr_t)out;
        srd.x = (uint32_t)op;
        srd.y = (uint32_t)(op >> 32);
        srd.z = outBytes;
        srd.w = 0x00020000u;
    }

    int a = ((SSPAN - SLAB) * w / 7 + 1) & ~1;

    float c0, sk0, c1, sk1;
    {
        const f32x4* u4 = (const f32x4*)uin;
        const f32x4 u = u4[(blockBase + a + lane * 2) >> 1];
        c0 = u.x; sk0 = u.y; c1 = u.z; sk1 = u.w;
    }

    __syncthreads();   // slut ready

    int done = 0;
    while (done < T) {
        int nst = T - done; if (nst > EPOCH) nst = EPOCH;
        const int si = a + lane * 2;
        const int g0 = blockBase + si;

        float K0_0 = 0.0f, K1_0 = K1u, K2_0 = K2u;
        const float K3_0 = K3u;
        float K1_1 = K1u, K3_1 = K3u;
        const float K2_1 = K2u;
        if (g0 == 0)           { K0_0 = dt * BC * (2.0f * A * s1 + B);
                                 K1_0 = dt * (3.0f * A * s0 - B); K2_0 = 0.0f; }
        if (g0 + 1 == NXS - 1) { K1_1 = dt * (2.0f * A * s0 - B + A * s1);
                                 K3_1 = 0.0f; }

        const int vL = leftA ? 0 : done;
        const int vR = rightA ? SSPAN : SSPAN - done;
        const int pd = vR - vL - SLAB;
        const int aPrev = vL + ((pd * (w - 1) / 7 + 1) & ~1);
        const int aNext = vL + ((pd * (w + 1) / 7 + 1) & ~1);
        int bLo = (w == 0) ? 0     : (((aPrev + SLAB + a) >> 1) & ~1);
        int bHi = (w == 7) ? SSPAN : (((a + SLAB + aNext) >> 1) & ~1);
        if (bLo < ownRelL) bLo = ownRelL;
        if (bHi > ownRelR) bHi = ownRelR;
        const bool st = (si >= bLo) && (si < bHi);
        uint32_t voff = st ? (uint32_t)((done * NXS + g0) * 8) : 0x60000000u;

        // epoch prologue: fetch linearization at current c (exact for iter 0)
        float clS = dpp_up(c1);
        float crS = dpp_down(c0);
        int i0 = (int)__builtin_amdgcn_fmed3f(fmaf(c0, LUT_SC, LUT_BF), 0.0f, 511.0f);
        int i1 = (int)__builtin_amdgcn_fmed3f(fmaf(c1, LUT_SC, LUT_BF), 0.0f, 511.0f);
        f32x4 E0 = slut[(i0 << 4) | r15];
        f32x4 E1 = slut[(i1 << 4) | r15];

        if (done < SAFE_T) {
            // ---- EXACT mode (R15 pattern): fetch after update, same-bin lerp ----
            for (int s = 0; s < nst; ++s) {
                float t0 = fmaf(K1_0, c0, K0_0);
                t0 = fmaf(K2_0, clS, t0);
                t0 = fmaf(K3_0, c1, t0);
                float t1 = K1_1 * c1;
                t1 = fmaf(K2_1, c0, t1);
                t1 = fmaf(K3_1, crS, t1);

                const float ret0 = fmaf(c0, E0.x, E0.y);
                const float pw0  = fmaf(c0, E0.z, E0.w);
                const float ret1 = fmaf(c1, E1.x, E1.y);
                const float pw1  = fmaf(c1, E1.z, E1.w);

                float v0 = fmaf(ret0, t0, c0); v0 = fmaf(mGAKD, pw0, v0);
                float v1 = fmaf(ret1, t1, c1); v1 = fmaf(mGAKD, pw1, v1);
                const float nc0 = fmaf(G, sk0, v0);
                const float nc1 = fmaf(G, sk1, v1);
                sk0 = fmaf(S1c, sk0, S2c * pw0);
                sk1 = fmaf(S1c, sk1, S2c * pw1);
                c0 = nc0; c1 = nc1;

                i0 = (int)__builtin_amdgcn_fmed3f(fmaf(c0, LUT_SC, LUT_BF), 0.0f, 511.0f);
                i1 = (int)__builtin_amdgcn_fmed3f(fmaf(c1, LUT_SC, LUT_BF), 0.0f, 511.0f);
                E0 = slut[(i0 << 4) | r15];
                E1 = slut[(i1 << 4) | r15];
                clS = dpp_up(c1);
                crS = dpp_down(c0);

                f32x4 ov; ov.x = c0; ov.y = sk0; ov.z = c1; ov.w = sk1;
                asm volatile("buffer_store_dwordx4 %0, %1, %2, 0 offen"
                             :: "v"(ov), "v"(voff), "s"(srd) : "memory");
                voff += (uint32_t)(NXS * 8);
            }
        } else {
            // ---- LAG mode: fetch at top (bin of current c), consume next iter ----
            for (int s = 0; s < nst; ++s) {
                const int n0 = (int)__builtin_amdgcn_fmed3f(fmaf(c0, LUT_SC, LUT_BF), 0.0f, 511.0f);
                const int n1 = (int)__builtin_amdgcn_fmed3f(fmaf(c1, LUT_SC, LUT_BF), 0.0f, 511.0f);
                const f32x4 EN0 = slut[(n0 << 4) | r15];   // full body of slack
                const f32x4 EN1 = slut[(n1 << 4) | r15];

                float t0 = fmaf(K1_0, c0, K0_0);
                t0 = fmaf(K2_0, clS, t0);
                t0 = fmaf(K3_0, c1, t0);
                float t1 = K1_1 * c1;
                t1 = fmaf(K2_1, c0, t1);
                t1 = fmaf(K3_1, crS, t1);

                // E: linearization from last step's bin, evaluated at current c
                const float ret0 = fmaf(c0, E0.x, E0.y);
                const float pw0  = fmaf(c0, E0.z, E0.w);
                const float ret1 = fmaf(c1, E1.x, E1.y);
                const float pw1  = fmaf(c1, E1.z, E1.w);

                float v0 = fmaf(ret0, t0, c0); v0 = fmaf(mGAKD, pw0, v0);
                float v1 = fmaf(ret1, t1, c1); v1 = fmaf(mGAKD, pw1, v1);
                const float nc0 = fmaf(G, sk0, v0);
                const float nc1 = fmaf(G, sk1, v1);
                sk0 = fmaf(S1c, sk0, S2c * pw0);
                sk1 = fmaf(S1c, sk1, S2c * pw1);
                c0 = nc0; c1 = nc1;

                clS = dpp_up(c1);
                crS = dpp_down(c0);
                E0 = EN0; E1 = EN1;

                f32x4 ov; ov.x = c0; ov.y = sk0; ov.z = c1; ov.w = sk1;
                asm volatile("buffer_store_dwordx4 %0, %1, %2, 0 offen"
                             :: "v"(ov), "v"(voff), "s"(srd) : "memory");
                voff += (uint32_t)(NXS * 8);
            }
        }

        done += nst;
        if (done >= T) break;

        // ---- refill: LDS-only barriers (stores stay in flight) ----
        asm volatile("s_waitcnt lgkmcnt(0)" ::: "memory");
        __builtin_amdgcn_s_barrier();
        asm volatile("" ::: "memory");
        {
            const int wLo = (w == 0 && leftA)  ? 0    : EPOCH;
            const int wHi = (w == 7 && rightA) ? SLAB : SLAB - EPOCH;
            const int sr = lane * 2;
            if (sr >= wLo && sr < wHi)         xbuf[a + sr]     = make_float2(c0, sk0);
            if (sr + 1 >= wLo && sr + 1 < wHi) xbuf[a + sr + 1] = make_float2(c1, sk1);
        }
        asm volatile("s_waitcnt lgkmcnt(0)" ::: "memory");
        __builtin_amdgcn_s_barrier();
        asm volatile("" ::: "memory");
        {
            const int vL2 = leftA ? 0 : done;
            const int vR2 = rightA ? SSPAN : SSPAN - done;
            const int pd2 = vR2 - vL2 - SLAB;
            a = vL2 + ((pd2 * w / 7 + 1) & ~1);
            const f32x4 u = *(const f32x4*)&xbuf[a + lane * 2];
            c0 = u.x; sk0 = u.y; c1 = u.z; sk1 = u.w;
        }
        asm volatile("s_waitcnt lgkmcnt(0)" ::: "memory");
        __builtin_amdgcn_s_barrier();
        asm volatile("" ::: "memory");
    }
}

extern "C" void kernel_launch(void* const* d_in, const int* in_sizes, int n_in,
                              void* d_out, int out_size, void* d_ws, size_t ws_size,
                              hipStream_t stream)
{
    const float* u0 = (const float*)d_in[0];
    FinnPtrs P;
    P.tvec    = (const float*)d_in[1];
    const float* W0      = (const float*)d_in[2];
    const float* b0      = (const float*)d_in[3];
    const float* W1      = (const float*)d_in[4];
    const float* b1      = (const float*)d_in[5];
    const float* W2      = (const float*)d_in[6];
    const float* b2      = (const float*)d_in[7];
    const float* W3      = (const float*)d_in[8];
    const float* b3      = (const float*)d_in[9];
    const float* ret_fac = (const float*)d_in[10];
    P.Dp      = (const float*)d_in[11];
    P.stencil = (const float*)d_in[12];
    P.BCp     = (const float*)d_in[13];
    P.fp      = (const float*)d_in[14];
    P.kdp     = (const float*)d_in[15];
    P.betap   = (const float*)d_in[16];
    P.alphap  = (const float*)d_in[17];
    P.rhosp   = (const float*)d_in[18];
    P.nep     = (const float*)d_in[19];
    P.vep     = (const float*)d_in[20];
    P.dxp     = (const float*)d_in[21];

    float*  out = (float*)d_out;
    float2* raw = (float2*)d_ws;        // (LUT_N+1) float2 nodes
    const int T = in_sizes[1];          // 200

    hipLaunchKernelGGL(finn_lut, dim3((LUT_N + 1 + 255) / 256), dim3(256), 0,
                       stream, W0, b0, W1, b1, W2, b2, W3, b3, ret_fac,
                       P.betap, raw);

    hipLaunchKernelGGL(finn_sweep, dim3(NB), dim3(BTL), 0, stream,
                       u0, out, raw, P, T, (uint32_t)out_size * 4u);
}

// Round 18
// 63.177 us; speedup vs baseline: 1.3336x; 1.0482x over previous
//
#include <hip/hip_runtime.h>
#include <stdint.h>

#define NXS    65536
#define HID    32
#define BTL    512           // 8 waves per block
#define NB     256           // 1 block/CU
#define OWNB   256           // cells owned per block
#define MARG   200           // halo per side (single launch, T=200)
#define SSPAN  656           // cells spanned per block
#define SLAB   128           // cells per wave slab (2 per lane)
#define EPOCH  24            // steps between refills (even!)
#define LUT_N  1024          // entries over [-0.25, 1.75]
#define NREP   16            // bank-interleaved copies
#define LUT_SC   512.0f      // entries per unit c
#define LUT_BF   128.0f      // -lo * scale = 0.25*512

typedef float    f32x4 __attribute__((ext_vector_type(4)));
typedef uint32_t u32x4 __attribute__((ext_vector_type(4)));

__device__ __forceinline__ float fexp2(float x) { return __builtin_amdgcn_exp2f(x); }
__device__ __forceinline__ float frcp(float x)  { return __builtin_amdgcn_rcpf(x); }
__device__ __forceinline__ float flog2(float x) { return __builtin_amdgcn_logf(x); }

// DPP wave shifts (VALU pipe)
__device__ __forceinline__ float dpp_up(float x) {
    int xi = __float_as_int(x);
    return __int_as_float(__builtin_amdgcn_update_dpp(xi, xi, 0x138, 0xF, 0xF, false));
}
__device__ __forceinline__ float dpp_down(float x) {
    int xi = __float_as_int(x);
    return __int_as_float(__builtin_amdgcn_update_dpp(xi, xi, 0x130, 0xF, 0xF, false));
}

__device__ __forceinline__ float fast_tanh(float x) {
    x = fminf(fmaxf(x, -15.0f), 15.0f);
    float e = fexp2(x * 2.8853900817779268f);
    return (e - 1.0f) * frcp(e + 1.0f);
}
__device__ __forceinline__ float fast_sigmoid(float x) {
    float e = fexp2(x * -1.4426950408889634f);
    return frcp(1.0f + e);
}

struct FinnPtrs {
    const float* tvec;
    const float* Dp;  const float* stencil; const float* BCp; const float* fp;
    const float* kdp; const float* betap;   const float* alphap; const float* rhosp;
    const float* nep; const float* vep;     const float* dxp;
};

// ---- Kernel 1: build replicated (ret, pw) midpoint LUT in ws ----
__global__ __launch_bounds__(256) void finn_lut(
    const float* __restrict__ W0, const float* __restrict__ b0,
    const float* __restrict__ W1, const float* __restrict__ b1,
    const float* __restrict__ W2, const float* __restrict__ b2,
    const float* __restrict__ W3, const float* __restrict__ b3,
    const float* __restrict__ ret_fac, const float* __restrict__ betap,
    float2* __restrict__ rep)
{
    const int i = blockIdx.x * 256 + threadIdx.x;
    if (i >= LUT_N) return;
    const float c = -0.25f + ((float)i + 0.5f) * (1.0f / LUT_SC);

    float h[HID], a[HID];
    #pragma unroll
    for (int j = 0; j < HID; ++j)
        h[j] = fast_tanh(fmaf(c, W0[j], b0[j]));

    #pragma unroll
    for (int j = 0; j < HID; ++j) a[j] = b1[j];
    #pragma unroll
    for (int k = 0; k < HID; ++k) {
        const float hk = h[k];
        #pragma unroll
        for (int j = 0; j < HID; ++j) a[j] = fmaf(hk, W1[k * HID + j], a[j]);
    }
    #pragma unroll
    for (int j = 0; j < HID; ++j) h[j] = fast_tanh(a[j]);

    #pragma unroll
    for (int j = 0; j < HID; ++j) a[j] = b2[j];
    #pragma unroll
    for (int k = 0; k < HID; ++k) {
        const float hk = h[k];
        #pragma unroll
        for (int j = 0; j < HID; ++j) a[j] = fmaf(hk, W2[k * HID + j], a[j]);
    }
    #pragma unroll
    for (int j = 0; j < HID; ++j) h[j] = fast_tanh(a[j]);

    float pre = b3[0];
    #pragma unroll
    for (int k = 0; k < HID; ++k) pre = fmaf(h[k], W3[k], pre);

    const float ret = fast_sigmoid(pre) * ret_fac[0];
    const float pw  = fexp2(betap[0] * flog2(fmaxf(c, 1e-9f)));
    const float2 e = make_float2(ret, pw);
    #pragma unroll
    for (int r = 0; r < NREP; ++r)
        rep[i * NREP + r] = e;
}

// ---- Kernel 2: R15 structure; ONLY change: exec-predicated stores ----
__global__ __launch_bounds__(BTL, 2) void finn_sweep(
    const float* __restrict__ uin, float* __restrict__ out,
    const float2* __restrict__ rep_g, FinnPtrs P, int T, uint32_t outBytes)
{
    __shared__ float2 slut[LUT_N * NREP];   // 128 KB, bank-interleaved copies
    __shared__ float2 xbuf[SSPAN];          // refill exchange

    const int tid  = threadIdx.x;
    const int w    = tid >> 6;
    const int lane = tid & 63;
    const int r15  = lane & 15;

    // stage replicated LUT
    {
        const f32x4* src4 = (const f32x4*)rep_g;
        f32x4* dst4 = (f32x4*)slut;
        #pragma unroll
        for (int j = 0; j < (LUT_N * NREP * 8 / 16) / BTL; ++j)
            dst4[tid + j * BTL] = src4[tid + j * BTL];
    }

    // wave-uniform scalars
    const float dt   = P.tvec[1] - P.tvec[0];
    const float s0   = P.stencil[0];
    const float s1   = P.stencil[1];
    const float dx   = P.dxp[0];
    const float A    = P.Dp[0] / (dx * dx);
    const float B    = P.vep[0] / dx;
    const float BC   = P.BCp[0];
    const float alp  = P.alphap[0];
    const float akd  = (1.0f - P.fp[0]) * P.kdp[0];
    const float rsne = P.rhosp[0] / P.nep[0];

    const float G     = dt * rsne * alp;
    const float mGAKD = -G * akd;
    const float S1c   = 1.0f - dt * alp;
    const float S2c   = dt * alp * akd;
    const float K1u   = dt * (2.0f * A * s0 - B);
    const float K2u   = dt * (A * s1 + B);
    const float K3u   = dt * A * s1;

    const int b = blockIdx.x;
    int blockBase = b * OWNB - MARG;
    if (blockBase < 0) blockBase = 0;
    if (blockBase > NXS - SSPAN) blockBase = NXS - SSPAN;
    const bool leftA  = (blockBase == 0);
    const bool rightA = (blockBase == NXS - SSPAN);
    const int ownRelL = b * OWNB - blockBase;
    const int ownRelR = ownRelL + OWNB;

    u32x4 srd;
    {
        const uint64_t op = (uint64_t)(uintptr_t)out;
        srd.x = (uint32_t)op;
        srd.y = (uint32_t)(op >> 32);
        srd.z = outBytes;
        srd.w = 0x00020000u;
    }

    // epoch-0 slab base (even)
    int a = ((SSPAN - SLAB) * w / 7 + 1) & ~1;

    float c0, sk0, c1, sk1;
    {
        const f32x4* u4 = (const f32x4*)uin;
        const f32x4 u = u4[(blockBase + a + lane * 2) >> 1];
        c0 = u.x; sk0 = u.y; c1 = u.z; sk1 = u.w;
    }

    __syncthreads();   // slut ready

    int done = 0;
    while (done < T) {
        int nst = T - done; if (nst > EPOCH) nst = EPOCH;
        const int si = a + lane * 2;      // even
        const int g0 = blockBase + si;

        // folded K constants
        float K0_0 = 0.0f, K1_0 = K1u, K2_0 = K2u;
        const float K3_0 = K3u;
        float K1_1 = K1u, K3_1 = K3u;
        const float K2_1 = K2u;
        if (g0 == 0)           { K0_0 = dt * BC * (2.0f * A * s1 + B);
                                 K1_0 = dt * (3.0f * A * s0 - B); K2_0 = 0.0f; }
        if (g0 + 1 == NXS - 1) { K1_1 = dt * (2.0f * A * s0 - B + A * s1);
                                 K3_1 = 0.0f; }

        // store window
        const int vL = leftA ? 0 : done;
        const int vR = rightA ? SSPAN : SSPAN - done;
        const int pd = vR - vL - SLAB;
        const int aPrev = vL + ((pd * (w - 1) / 7 + 1) & ~1);
        const int aNext = vL + ((pd * (w + 1) / 7 + 1) & ~1);
        int bLo = (w == 0) ? 0     : (((aPrev + SLAB + a) >> 1) & ~1);
        int bHi = (w == 7) ? SSPAN : (((a + SLAB + aNext) >> 1) & ~1);
        if (bLo < ownRelL) bLo = ownRelL;
        if (bHi > ownRelR) bHi = ownRelR;
        const bool st = (si >= bLo) && (si < bHi);
        uint32_t voff = (uint32_t)((done * NXS + g0) * 8);

        // prologue comms
        float clS = dpp_up(c1);
        float crS = dpp_down(c0);
        int i0 = (int)__builtin_amdgcn_fmed3f(fmaf(c0, LUT_SC, LUT_BF), 0.0f, 1023.0f);
        int i1 = (int)__builtin_amdgcn_fmed3f(fmaf(c1, LUT_SC, LUT_BF), 0.0f, 1023.0f);
        float2 E0 = slut[(i0 << 4) | r15];
        float2 E1 = slut[(i1 << 4) | r15];

        for (int s = 0; s < nst; ++s) {
            float t0 = fmaf(K1_0, c0, K0_0);
            t0 = fmaf(K2_0, clS, t0);
            t0 = fmaf(K3_0, c1, t0);
            float t1 = K1_1 * c1;
            t1 = fmaf(K2_1, c0, t1);
            t1 = fmaf(K3_1, crS, t1);

            float v0 = fmaf(E0.x, t0, c0); v0 = fmaf(mGAKD, E0.y, v0);
            float v1 = fmaf(E1.x, t1, c1); v1 = fmaf(mGAKD, E1.y, v1);
            const float nc0 = fmaf(G, sk0, v0);
            const float nc1 = fmaf(G, sk1, v1);
            sk0 = fmaf(S1c, sk0, S2c * E0.y);
            sk1 = fmaf(S1c, sk1, S2c * E1.y);
            c0 = nc0; c1 = nc1;

            // prefetch for s+1
            i0 = (int)__builtin_amdgcn_fmed3f(fmaf(c0, LUT_SC, LUT_BF), 0.0f, 1023.0f);
            i1 = (int)__builtin_amdgcn_fmed3f(fmaf(c1, LUT_SC, LUT_BF), 0.0f, 1023.0f);
            E0 = slut[(i0 << 4) | r15];
            E1 = slut[(i1 << 4) | r15];
            clS = dpp_up(c1);
            crS = dpp_down(c0);

            // EXEC-PREDICATED store: inactive lanes issue NO address traffic
            if (st) {
                f32x4 ov; ov.x = c0; ov.y = sk0; ov.z = c1; ov.w = sk1;
                asm volatile("buffer_store_dwordx4 %0, %1, %2, 0 offen"
                             :: "v"(ov), "v"(voff), "s"(srd) : "memory");
            }
            voff += (uint32_t)(NXS * 8);
        }

        done += nst;
        if (done >= T) break;

        // ---- refill: LDS-only barriers (stores stay in flight) ----
        asm volatile("s_waitcnt lgkmcnt(0)" ::: "memory");
        __builtin_amdgcn_s_barrier();
        asm volatile("" ::: "memory");
        {
            const int wLo = (w == 0 && leftA)  ? 0    : EPOCH;
            const int wHi = (w == 7 && rightA) ? SLAB : SLAB - EPOCH;
            const int sr = lane * 2;
            if (sr >= wLo && sr < wHi)         xbuf[a + sr]     = make_float2(c0, sk0);
            if (sr + 1 >= wLo && sr + 1 < wHi) xbuf[a + sr + 1] = make_float2(c1, sk1);
        }
        asm volatile("s_waitcnt lgkmcnt(0)" ::: "memory");
        __builtin_amdgcn_s_barrier();
        asm volatile("" ::: "memory");
        {
            const int vL2 = leftA ? 0 : done;
            const int vR2 = rightA ? SSPAN : SSPAN - done;
            const int pd2 = vR2 - vL2 - SLAB;
            a = vL2 + ((pd2 * w / 7 + 1) & ~1);
            const f32x4 u = *(const f32x4*)&xbuf[a + lane * 2];
            c0 = u.x; sk0 = u.y; c1 = u.z; sk1 = u.w;
        }
        asm volatile("s_waitcnt lgkmcnt(0)" ::: "memory");
        __builtin_amdgcn_s_barrier();
        asm volatile("" ::: "memory");
    }
}

extern "C" void kernel_launch(void* const* d_in, const int* in_sizes, int n_in,
                              void* d_out, int out_size, void* d_ws, size_t ws_size,
                              hipStream_t stream)
{
    const float* u0 = (const float*)d_in[0];
    FinnPtrs P;
    P.tvec    = (const float*)d_in[1];
    const float* W0      = (const float*)d_in[2];
    const float* b0      = (const float*)d_in[3];
    const float* W1      = (const float*)d_in[4];
    const float* b1      = (const float*)d_in[5];
    const float* W2      = (const float*)d_in[6];
    const float* b2      = (const float*)d_in[7];
    const float* W3      = (const float*)d_in[8];
    const float* b3      = (const float*)d_in[9];
    const float* ret_fac = (const float*)d_in[10];
    P.Dp      = (const float*)d_in[11];
    P.stencil = (const float*)d_in[12];
    P.BCp     = (const float*)d_in[13];
    P.fp      = (const float*)d_in[14];
    P.kdp     = (const float*)d_in[15];
    P.betap   = (const float*)d_in[16];
    P.alphap  = (const float*)d_in[17];
    P.rhosp   = (const float*)d_in[18];
    P.nep     = (const float*)d_in[19];
    P.vep     = (const float*)d_in[20];
    P.dxp     = (const float*)d_in[21];

    float*  out = (float*)d_out;
    float2* rep = (float2*)d_ws;        // 128 KB replicated LUT
    const int T = in_sizes[1];          // 200

    hipLaunchKernelGGL(finn_lut, dim3(LUT_N / 256), dim3(256), 0, stream,
                       W0, b0, W1, b1, W2, b2, W3, b3, ret_fac, P.betap, rep);

    hipLaunchKernelGGL(finn_sweep, dim3(NB), dim3(BTL), 0, stream,
                       u0, out, rep, P, T, (uint32_t)out_size * 4u);
}